// Round 13
// baseline (111.560 us; speedup 1.0000x reference)
//
#include <hip/hip_runtime.h>
#include <hip/hip_bf16.h>
#include <cstdint>

// ---------------------------------------------------------------------------
// Fused causal self-attention block (B=2, T=2048, C=1024, H=16, Dh=64), fp32 in/out.
// cvt fp32->bf16 -> QKV GEMM (Q pre-scaled, V written transposed) -> flash attn -> out GEMM.
// Workspace (48MB):
//   yb    @ 0     8 MB   bf16 x (xb) -> DEAD after gemm1 -> reused as yb
//   wqkvb @ 8 MB  6 MB   bf16 w_qkv [3072][1024]
//   wob   @ 14MB  2 MB   bf16 w_out [1024][1024]
//   qkvb  @ 16MB 24 MB   bf16 qkv [4096][3072] (Q scaled | K | V-region unused)
//   vt    @ 40MB  8 MB   bf16 Vt [32 bh][64 d][2048 t] (written by gemm1 epilogue)
// ---------------------------------------------------------------------------

typedef __bf16 bf16x8 __attribute__((ext_vector_type(8)));
typedef float  f32x4  __attribute__((ext_vector_type(4)));
typedef unsigned short u16x4 __attribute__((ext_vector_type(4)));

#define EMB   1024
#define HEADS 16
#define HD    64
#define TT    2048
#define NROWS 4096
#define QKVN  3072
#define SCL   0.18033688f   /* 0.125 * log2(e): folded into Q at gemm1 epilogue */
#define THR   11.0f         /* defer-max threshold, log2 units */

// ---- fused fp32 -> bf16 (8 elems / thread, 3 arrays in one launch) ----
__global__ void cvt_all(const float* __restrict__ x, const float* __restrict__ wq,
                        const float* __restrict__ wo, __bf16* __restrict__ xb,
                        __bf16* __restrict__ wqb, __bf16* __restrict__ wob) {
  const int bid = blockIdx.x;
  const float* in; __bf16* out; int i;
  if (bid < 2048)      { in = x;  out = xb;  i = bid * 256 + threadIdx.x; }
  else if (bid < 3584) { in = wq; out = wqb; i = (bid - 2048) * 256 + threadIdx.x; }
  else                 { in = wo; out = wob; i = (bid - 3584) * 256 + threadIdx.x; }
  const float4* p = (const float4*)in + (size_t)i * 2;
  float4 a = p[0], b = p[1];
  bf16x8 o;
  o[0] = (__bf16)a.x; o[1] = (__bf16)a.y; o[2] = (__bf16)a.z; o[3] = (__bf16)a.w;
  o[4] = (__bf16)b.x; o[5] = (__bf16)b.y; o[6] = (__bf16)b.z; o[7] = (__bf16)b.w;
  *((bf16x8*)out + i) = o;
}

__device__ __forceinline__ void gload_lds16(const void* g, void* l) {
  __builtin_amdgcn_global_load_lds(
      (const __attribute__((address_space(1))) void*)(uintptr_t)g,
      (__attribute__((address_space(3))) void*)(uint32_t)(uintptr_t)l,
      16, 0, 0);
}

// ---------------------------------------------------------------------------
// GEMM (R12): 128x128 tile, BK=64, chunk-swizzled staging, XCD swizzle.
// MODE 1 epilogue: Q scaled, K plain, V transposed to vt.
// ---------------------------------------------------------------------------
template <int MODE>
__global__ __launch_bounds__(256, 2)
void gemm_bt(const __bf16* __restrict__ A, const __bf16* __restrict__ Bm,
             void* __restrict__ Cout, __bf16* __restrict__ vt,
             int M, int N, int K) {
  __shared__ __align__(16) char As[128 * 128];
  __shared__ __align__(16) char Bs[128 * 128];
  const int tid  = threadIdx.x;
  const int lane = tid & 63;
  const int wid  = tid >> 6;
  const int wr = wid >> 1, wc = wid & 1;
  const int nwg = gridDim.x * gridDim.y;
  int flat = blockIdx.y * gridDim.x + blockIdx.x;
  flat = (flat & 7) * (nwg >> 3) + (flat >> 3);
  const int brow = (flat / gridDim.x) * 128;
  const int bcol = (flat % gridDim.x) * 128;
  const int fr = lane & 15, g = lane >> 4;

  f32x4 acc[4][4];
#pragma unroll
  for (int m = 0; m < 4; m++)
#pragma unroll
    for (int n = 0; n < 4; n++)
#pragma unroll
      for (int r = 0; r < 4; r++) acc[m][n][r] = 0.0f;

  for (int k0 = 0; k0 < K; k0 += 64) {
    __syncthreads();
#pragma unroll
    for (int i = 0; i < 4; i++) {
      const int c = tid + i * 256;
      const int row = c >> 3, pos = c & 7;
      const int sc = pos ^ (row & 7);
      gload_lds16(A  + (size_t)(brow + row) * K + k0 + sc * 8, As + c * 16);
      gload_lds16(Bm + (size_t)(bcol + row) * K + k0 + sc * 8, Bs + c * 16);
    }
    __syncthreads();

    bf16x8 af[4][2], bfr[4][2];
#pragma unroll
    for (int m = 0; m < 4; m++)
#pragma unroll
      for (int kc = 0; kc < 2; kc++) {
        const int row = wr * 64 + m * 16 + fr;
        af[m][kc] = *(const bf16x8*)(As + row * 128 + (((kc << 2) | g) ^ (fr & 7)) * 16);
      }
#pragma unroll
    for (int n = 0; n < 4; n++)
#pragma unroll
      for (int kc = 0; kc < 2; kc++) {
        const int row = wc * 64 + n * 16 + fr;
        bfr[n][kc] = *(const bf16x8*)(Bs + row * 128 + (((kc << 2) | g) ^ (fr & 7)) * 16);
      }
#pragma unroll
    for (int kc = 0; kc < 2; kc++)
#pragma unroll
      for (int m = 0; m < 4; m++)
#pragma unroll
        for (int n = 0; n < 4; n++)
          acc[m][n] = __builtin_amdgcn_mfma_f32_16x16x32_bf16(af[m][kc], bfr[n][kc], acc[m][n], 0, 0, 0);
  }

  const int rbase = brow + wr * 64 + g * 4;
  const int cbase = bcol + wc * 64 + fr;
  if (MODE == 0) {
#pragma unroll
    for (int m = 0; m < 4; m++)
#pragma unroll
      for (int n = 0; n < 4; n++) {
        const int col = cbase + n * 16;
#pragma unroll
        for (int r = 0; r < 4; r++)
          ((float*)Cout)[(size_t)(rbase + m * 16 + r) * N + col] = acc[m][n][r];
      }
  } else if (bcol < 2 * EMB) {
    const float qscale = (bcol < EMB) ? SCL : 1.0f;
#pragma unroll
    for (int m = 0; m < 4; m++)
#pragma unroll
      for (int n = 0; n < 4; n++) {
        const int col = cbase + n * 16;
#pragma unroll
        for (int r = 0; r < 4; r++)
          ((__bf16*)Cout)[(size_t)(rbase + m * 16 + r) * N + col] = (__bf16)(acc[m][n][r] * qscale);
      }
  } else {
#pragma unroll
    for (int m = 0; m < 4; m++) {
      const int row0 = rbase + m * 16;
      const int b = row0 >> 11, t0 = row0 & 2047;
#pragma unroll
      for (int n = 0; n < 4; n++) {
        const int vcol = cbase + n * 16 - 2 * EMB;
        const int bh = b * HEADS + (vcol >> 6);
        const int d  = vcol & 63;
        u16x4 pk;
#pragma unroll
        for (int r = 0; r < 4; r++) {
          const __bf16 h = (__bf16)acc[m][n][r];
          pk[r] = *(const unsigned short*)&h;
        }
        *(u16x4*)(vt + ((size_t)bh * HD + d) * TT + t0) = pk;
      }
    }
  }
}

// ---------------------------------------------------------------------------
// Causal flash attention v13 = v9 pipeline with 32-q-row waves.
//   - Wave owns 32 q rows (2 m-frags); block = 4 waves = 128-row chunk.
//     K/V LDS bytes per unit work drop 45% (each wave reads the full 8KB
//     K and V tile for 2x the q rows).  grid = 512 (16 pos x 32 bh), LPT.
//   - 4-deep K/V buffers, counted s_waitcnt vmcnt(4); cross-tile pipeline
//     (QK(t+1) | PV(t) | softmax(t+1)); P [32][128B] round-trip spans a
//     phase; defer-max; ones-MFMA row-sum; raw v_exp_f32; Q pre-scaled.
//   - s_setprio(1) around MFMA clusters (T5).
//   - Waves 0,1 skip the block's final tile (diag geometry); barriers kept.
// LDS 80KB -> 2 blocks/CU.
// ---------------------------------------------------------------------------
__device__ __forceinline__ int psw(int row) {
  return (((row & 7) ^ ((row >> 3) & 7))) << 4;
}

__global__ __launch_bounds__(256, 2)
void attn_causal13(const __bf16* __restrict__ qkv, const __bf16* __restrict__ vt,
                   __bf16* __restrict__ yb) {
  __shared__ __align__(16) char Kbuf[4][8192];   // K[kv][d], chunk-swizzled
  __shared__ __align__(16) char Vbuf[4][8192];   // Vt[d][kv], chunk-swizzled
  __shared__ __align__(16) char Pbuf[4][4096];   // per-wave P[32][64], psw-swizzled

  const int tid = threadIdx.x;
  const int lane = tid & 63, w = tid >> 6;
  const int L = blockIdx.x;
  const int bh = L & 31;
  const int chunk = 15 - (L >> 5);               // LPT: longest first
  const int b = bh >> 4, h = bh & 15;
  const size_t rowbase = (size_t)b * TT;
  const int q0 = chunk * 128 + w * 32;           // wave's first q row
  const int fr = lane & 15, g = lane >> 4;
  const int ntiles = 2 * chunk + 2;
  const int tmaxw = (q0 + 31) >> 6;              // wave's last active tile

  bf16x8 qf[2][2];
#pragma unroll
  for (int m2 = 0; m2 < 2; m2++)
#pragma unroll
    for (int kc = 0; kc < 2; kc++)
      qf[m2][kc] = *(const bf16x8*)(qkv + (rowbase + q0 + m2 * 16 + fr) * QKVN + h * HD + kc * 32 + g * 8);

  bf16x8 ones;
#pragma unroll
  for (int j = 0; j < 8; j++) ones[j] = (__bf16)1.0f;

  f32x4 o[2][4];
  f32x4 lacc[2];
  float m[2][4];
#pragma unroll
  for (int m2 = 0; m2 < 2; m2++) {
#pragma unroll
    for (int n = 0; n < 4; n++)
#pragma unroll
      for (int r = 0; r < 4; r++) o[m2][n][r] = 0.0f;
#pragma unroll
    for (int r = 0; r < 4; r++) { lacc[m2][r] = 0.0f; m[m2][r] = -1e30f; }
  }

  // 4 gload_lds per thread per stage -> vmcnt(4) = one stage in flight
  auto stageKV = [&](int kt, int buf) {
#pragma unroll
    for (int i = 0; i < 2; i++) {
      const int c = tid + i * 256;
      const int row = c >> 3;
      const int c16 = (c & 7) ^ (row & 7);
      gload_lds16(qkv + (rowbase + kt * 64 + row) * QKVN + EMB + h * HD + c16 * 8,
                  Kbuf[buf] + c * 16);
    }
#pragma unroll
    for (int i = 0; i < 2; i++) {
      const int c = tid + i * 256;
      const int row = c >> 3;
      const int c16 = (c & 7) ^ (row & 7);
      gload_lds16(vt + ((size_t)bh * HD + row) * TT + kt * 64 + c16 * 8,
                  Vbuf[buf] + c * 16);
    }
  };

  auto doQK = [&](int kt, f32x4 (&s)[2][4]) {
    const char* Kc = Kbuf[kt & 3];
    bf16x8 kf[4][2];
#pragma unroll
    for (int n = 0; n < 4; n++)
#pragma unroll
      for (int kc = 0; kc < 2; kc++) {
        const int row = n * 16 + fr;
        kf[n][kc] = *(const bf16x8*)(Kc + row * 128 + (((kc << 2) | g) ^ (row & 7)) * 16);
      }
    __builtin_amdgcn_s_setprio(1);
#pragma unroll
    for (int m2 = 0; m2 < 2; m2++)
#pragma unroll
      for (int n = 0; n < 4; n++) {
#pragma unroll
        for (int r = 0; r < 4; r++) s[m2][n][r] = 0.0f;
#pragma unroll
        for (int kc = 0; kc < 2; kc++)
          s[m2][n] = __builtin_amdgcn_mfma_f32_16x16x32_bf16(qf[m2][kc], kf[n][kc], s[m2][n], 0, 0, 0);
      }
    __builtin_amdgcn_s_setprio(0);
  };

  auto doSoftmax = [&](int kt, f32x4 (&s)[2][4]) {
    const int kv0 = kt * 64;
    if (kt == tmaxw) {                           // diagonal tile for this wave
#pragma unroll
      for (int m2 = 0; m2 < 2; m2++)
#pragma unroll
        for (int n = 0; n < 4; n++)
#pragma unroll
          for (int r = 0; r < 4; r++) {
            const int qg = q0 + m2 * 16 + g * 4 + r;
            const int kg = kv0 + n * 16 + fr;
            if (kg > qg) s[m2][n][r] = -1e30f;
          }
    }
    float pm[2][4];
#pragma unroll
    for (int m2 = 0; m2 < 2; m2++)
#pragma unroll
      for (int r = 0; r < 4; r++)
        pm[m2][r] = fmaxf(fmaxf(s[m2][0][r], s[m2][1][r]), fmaxf(s[m2][2][r], s[m2][3][r]));
    bool okl = true;
#pragma unroll
    for (int m2 = 0; m2 < 2; m2++)
#pragma unroll
      for (int r = 0; r < 4; r++)
        okl = okl && (pm[m2][r] <= m[m2][r] + THR);
    if (!__all(okl)) {
#pragma unroll
      for (int m2 = 0; m2 < 2; m2++)
#pragma unroll
        for (int r = 0; r < 4; r++) {
          float rm = pm[m2][r];
#pragma unroll
          for (int d = 1; d < 16; d <<= 1) rm = fmaxf(rm, __shfl_xor(rm, d, 16));
          const float nm = fmaxf(m[m2][r], rm);
          const float f = __builtin_amdgcn_exp2f(m[m2][r] - nm);
          m[m2][r] = nm;
          lacc[m2][r] *= f;
#pragma unroll
          for (int n = 0; n < 4; n++) o[m2][n][r] *= f;
        }
    }
#pragma unroll
    for (int m2 = 0; m2 < 2; m2++)
#pragma unroll
      for (int n = 0; n < 4; n++)
#pragma unroll
        for (int r = 0; r < 4; r++) {
          const float e = __builtin_amdgcn_exp2f(s[m2][n][r] - m[m2][r]);
          const int row = m2 * 16 + g * 4 + r;
          *(__bf16*)(Pbuf[w] + row * 128 + (((n * 16 + fr) * 2) ^ psw(row))) = (__bf16)e;
        }
  };

  auto doPV = [&](int kt) {
    const char* Vc = Vbuf[kt & 3];
    bf16x8 pa[2][2];
#pragma unroll
    for (int m2 = 0; m2 < 2; m2++)
#pragma unroll
      for (int kc = 0; kc < 2; kc++) {
        const int row = m2 * 16 + fr;
        pa[m2][kc] = *(const bf16x8*)(Pbuf[w] + row * 128 + ((kc * 64 + g * 16) ^ psw(row)));
      }
    bf16x8 vb[4][2];
#pragma unroll
    for (int n = 0; n < 4; n++)
#pragma unroll
      for (int kc = 0; kc < 2; kc++) {
        const int row = n * 16 + fr;
        vb[n][kc] = *(const bf16x8*)(Vc + row * 128 + (((kc << 2) | g) ^ (row & 7)) * 16);
      }
    __builtin_amdgcn_s_setprio(1);
#pragma unroll
    for (int m2 = 0; m2 < 2; m2++)
#pragma unroll
      for (int kc = 0; kc < 2; kc++) {
        lacc[m2] = __builtin_amdgcn_mfma_f32_16x16x32_bf16(pa[m2][kc], ones, lacc[m2], 0, 0, 0);
#pragma unroll
        for (int n = 0; n < 4; n++)
          o[m2][n] = __builtin_amdgcn_mfma_f32_16x16x32_bf16(pa[m2][kc], vb[n][kc], o[m2][n], 0, 0, 0);
      }
    __builtin_amdgcn_s_setprio(0);
  };

  // ---- prologue: fill pipeline (tiles 0..2), force 0,1 landed ----
  stageKV(0, 0);
  if (ntiles > 1) stageKV(1, 1);
  if (ntiles > 2) stageKV(2, 2);
  if (ntiles > 2) asm volatile("s_waitcnt vmcnt(4)" ::: "memory");
  else            asm volatile("s_waitcnt vmcnt(0)" ::: "memory");
  __builtin_amdgcn_s_barrier();

  {                                   // tile 0: QK + softmax (all waves active)
    f32x4 s0[2][4];
    doQK(0, s0);
    doSoftmax(0, s0);
  }

  for (int t = 0; t < ntiles; t++) {
    if (t + 3 < ntiles) stageKV(t + 3, (t + 3) & 3);

    const bool nxt = (t + 1 < ntiles) && (t + 1 <= tmaxw);
    f32x4 s[2][4];
    if (nxt) doQK(t + 1, s);          // overlaps PV(t)
    if (t <= tmaxw) doPV(t);          // consumes P(t) written last iter
    if (nxt) doSoftmax(t + 1, s);     // rescale o AFTER PV(t); writes P(t+1)

    if (t + 3 < ntiles) asm volatile("s_waitcnt vmcnt(4)" ::: "memory");
    else                asm volatile("s_waitcnt vmcnt(0)" ::: "memory");
    __builtin_amdgcn_s_barrier();
  }

#pragma unroll
  for (int m2 = 0; m2 < 2; m2++)
#pragma unroll
    for (int r = 0; r < 4; r++) {
      const float inv = __builtin_amdgcn_rcpf(lacc[m2][r]);
      const int q = q0 + m2 * 16 + g * 4 + r;
#pragma unroll
      for (int n = 0; n < 4; n++) {
        const int d = n * 16 + fr;
        yb[(rowbase + q) * EMB + h * HD + d] = (__bf16)(o[m2][n][r] * inv);
      }
    }
}

extern "C" void kernel_launch(void* const* d_in, const int* in_sizes, int n_in,
                              void* d_out, int out_size, void* d_ws, size_t ws_size,
                              hipStream_t stream) {
  const float* x     = (const float*)d_in[0];
  const float* w_qkv = (const float*)d_in[1];
  const float* w_out = (const float*)d_in[2];
  float* out = (float*)d_out;

  char* ws = (char*)d_ws;
  __bf16* xb    = (__bf16*)(ws);                 // dead after gemm1 -> reused as yb
  __bf16* wqkvb = (__bf16*)(ws + (8ull  << 20));
  __bf16* wob   = (__bf16*)(ws + (14ull << 20));
  __bf16* qkvb  = (__bf16*)(ws + (16ull << 20));
  __bf16* vtb   = (__bf16*)(ws + (40ull << 20));
  __bf16* yb    = xb;

  cvt_all<<<4096, 256, 0, stream>>>(x, w_qkv, w_out, xb, wqkvb, wob);
  gemm_bt<1><<<dim3(QKVN / 128, NROWS / 128), 256, 0, stream>>>(xb, wqkvb, qkvb, vtb, NROWS, QKVN, EMB);
  attn_causal13<<<512, 256, 0, stream>>>(qkvb, vtb, yb);
  gemm_bt<0><<<dim3(EMB / 128, NROWS / 128), 256, 0, stream>>>(yb, wob, out, nullptr, NROWS, EMB, EMB);
}

// Round 14
// 107.857 us; speedup vs baseline: 1.0343x; 1.0343x over previous
//
#include <hip/hip_runtime.h>
#include <hip/hip_bf16.h>
#include <cstdint>

// ---------------------------------------------------------------------------
// Fused causal self-attention block (B=2, T=2048, C=1024, H=16, Dh=64), fp32 in/out.
// cvt fp32->bf16 -> QKV GEMM (Q pre-scaled, V written transposed) -> flash attn -> out GEMM.
// Workspace (48MB):
//   yb    @ 0     8 MB   bf16 x (xb) -> DEAD after gemm1 -> reused as yb
//   wqkvb @ 8 MB  6 MB   bf16 w_qkv [3072][1024]
//   wob   @ 14MB  2 MB   bf16 w_out [1024][1024]
//   qkvb  @ 16MB 24 MB   bf16 qkv [4096][3072] (Q scaled | K | V-region unused)
//   vt    @ 40MB  8 MB   bf16 Vt [32 bh][64 d][2048 t] (written by gemm1 epilogue)
// ---------------------------------------------------------------------------

typedef __bf16 bf16x8 __attribute__((ext_vector_type(8)));
typedef float  f32x4  __attribute__((ext_vector_type(4)));
typedef unsigned short u16x4 __attribute__((ext_vector_type(4)));

#define EMB   1024
#define HEADS 16
#define HD    64
#define TT    2048
#define NROWS 4096
#define QKVN  3072
#define SCL   0.18033688f   /* 0.125 * log2(e): folded into Q at gemm1 epilogue */
#define THR   11.0f         /* defer-max threshold, log2 units */

// ---- fused fp32 -> bf16 (8 elems / thread, 3 arrays in one launch) ----
__global__ void cvt_all(const float* __restrict__ x, const float* __restrict__ wq,
                        const float* __restrict__ wo, __bf16* __restrict__ xb,
                        __bf16* __restrict__ wqb, __bf16* __restrict__ wob) {
  const int bid = blockIdx.x;
  const float* in; __bf16* out; int i;
  if (bid < 2048)      { in = x;  out = xb;  i = bid * 256 + threadIdx.x; }
  else if (bid < 3584) { in = wq; out = wqb; i = (bid - 2048) * 256 + threadIdx.x; }
  else                 { in = wo; out = wob; i = (bid - 3584) * 256 + threadIdx.x; }
  const float4* p = (const float4*)in + (size_t)i * 2;
  float4 a = p[0], b = p[1];
  bf16x8 o;
  o[0] = (__bf16)a.x; o[1] = (__bf16)a.y; o[2] = (__bf16)a.z; o[3] = (__bf16)a.w;
  o[4] = (__bf16)b.x; o[5] = (__bf16)b.y; o[6] = (__bf16)b.z; o[7] = (__bf16)b.w;
  *((bf16x8*)out + i) = o;
}

__device__ __forceinline__ void gload_lds16(const void* g, void* l) {
  __builtin_amdgcn_global_load_lds(
      (const __attribute__((address_space(1))) void*)(uintptr_t)g,
      (__attribute__((address_space(3))) void*)(uint32_t)(uintptr_t)l,
      16, 0, 0);
}

// ---------------------------------------------------------------------------
// GEMM (R12): 128x128 tile, BK=64, chunk-swizzled staging, XCD swizzle.
// MODE 1 epilogue: Q scaled, K plain, V transposed to vt.
// ---------------------------------------------------------------------------
template <int MODE>
__global__ __launch_bounds__(256, 2)
void gemm_bt(const __bf16* __restrict__ A, const __bf16* __restrict__ Bm,
             void* __restrict__ Cout, __bf16* __restrict__ vt,
             int M, int N, int K) {
  __shared__ __align__(16) char As[128 * 128];
  __shared__ __align__(16) char Bs[128 * 128];
  const int tid  = threadIdx.x;
  const int lane = tid & 63;
  const int wid  = tid >> 6;
  const int wr = wid >> 1, wc = wid & 1;
  const int nwg = gridDim.x * gridDim.y;
  int flat = blockIdx.y * gridDim.x + blockIdx.x;
  flat = (flat & 7) * (nwg >> 3) + (flat >> 3);
  const int brow = (flat / gridDim.x) * 128;
  const int bcol = (flat % gridDim.x) * 128;
  const int fr = lane & 15, g = lane >> 4;

  f32x4 acc[4][4];
#pragma unroll
  for (int m = 0; m < 4; m++)
#pragma unroll
    for (int n = 0; n < 4; n++)
#pragma unroll
      for (int r = 0; r < 4; r++) acc[m][n][r] = 0.0f;

  for (int k0 = 0; k0 < K; k0 += 64) {
    __syncthreads();
#pragma unroll
    for (int i = 0; i < 4; i++) {
      const int c = tid + i * 256;
      const int row = c >> 3, pos = c & 7;
      const int sc = pos ^ (row & 7);
      gload_lds16(A  + (size_t)(brow + row) * K + k0 + sc * 8, As + c * 16);
      gload_lds16(Bm + (size_t)(bcol + row) * K + k0 + sc * 8, Bs + c * 16);
    }
    __syncthreads();

    bf16x8 af[4][2], bfr[4][2];
#pragma unroll
    for (int m = 0; m < 4; m++)
#pragma unroll
      for (int kc = 0; kc < 2; kc++) {
        const int row = wr * 64 + m * 16 + fr;
        af[m][kc] = *(const bf16x8*)(As + row * 128 + (((kc << 2) | g) ^ (fr & 7)) * 16);
      }
#pragma unroll
    for (int n = 0; n < 4; n++)
#pragma unroll
      for (int kc = 0; kc < 2; kc++) {
        const int row = wc * 64 + n * 16 + fr;
        bfr[n][kc] = *(const bf16x8*)(Bs + row * 128 + (((kc << 2) | g) ^ (fr & 7)) * 16);
      }
#pragma unroll
    for (int kc = 0; kc < 2; kc++)
#pragma unroll
      for (int m = 0; m < 4; m++)
#pragma unroll
        for (int n = 0; n < 4; n++)
          acc[m][n] = __builtin_amdgcn_mfma_f32_16x16x32_bf16(af[m][kc], bfr[n][kc], acc[m][n], 0, 0, 0);
  }

  const int rbase = brow + wr * 64 + g * 4;
  const int cbase = bcol + wc * 64 + fr;
  if (MODE == 0) {
#pragma unroll
    for (int m = 0; m < 4; m++)
#pragma unroll
      for (int n = 0; n < 4; n++) {
        const int col = cbase + n * 16;
#pragma unroll
        for (int r = 0; r < 4; r++)
          ((float*)Cout)[(size_t)(rbase + m * 16 + r) * N + col] = acc[m][n][r];
      }
  } else if (bcol < 2 * EMB) {
    const float qscale = (bcol < EMB) ? SCL : 1.0f;
#pragma unroll
    for (int m = 0; m < 4; m++)
#pragma unroll
      for (int n = 0; n < 4; n++) {
        const int col = cbase + n * 16;
#pragma unroll
        for (int r = 0; r < 4; r++)
          ((__bf16*)Cout)[(size_t)(rbase + m * 16 + r) * N + col] = (__bf16)(acc[m][n][r] * qscale);
      }
  } else {
#pragma unroll
    for (int m = 0; m < 4; m++) {
      const int row0 = rbase + m * 16;
      const int b = row0 >> 11, t0 = row0 & 2047;
#pragma unroll
      for (int n = 0; n < 4; n++) {
        const int vcol = cbase + n * 16 - 2 * EMB;
        const int bh = b * HEADS + (vcol >> 6);
        const int d  = vcol & 63;
        u16x4 pk;
#pragma unroll
        for (int r = 0; r < 4; r++) {
          const __bf16 h = (__bf16)acc[m][n][r];
          pk[r] = *(const unsigned short*)&h;
        }
        *(u16x4*)(vt + ((size_t)bh * HD + d) * TT + t0) = pk;
      }
    }
  }
}

// ---------------------------------------------------------------------------
// Causal flash attention v14: 2-wave blocks, 32 q-rows/wave, 1024 blocks.
//   - LDS traffic per 64-q-row block-phase: 64KB (vs v9's 96KB, -33%) --
//     fragment reads scale with waves x tile bytes, so fewer/wider waves.
//   - LDS 40KB (2-deep K/V 32KB + 2x4KB P) -> 4 blocks/CU, 8 waves/CU.
//   - grid 1024 = 32 chunks x 32 bh; v4's constant-sum fold map
//     (p<16 ? p : 47-p): each CU's 4 blocks sum 62 chunks (measured flat).
//   - v4-style serial phase: stage(t+1) | QK(t) | SM(t) | PV(t) | barrier.
//     Same-wave DS in-order execution makes the P write->read safe.
//   - defer-max vote; ones-MFMA row-sum; raw v_exp_f32; Q pre-scaled;
//     s_setprio(1) around MFMA clusters.
// ---------------------------------------------------------------------------
__device__ __forceinline__ int psw(int row) {
  return (((row & 7) ^ ((row >> 3) & 7))) << 4;
}

__global__ __launch_bounds__(128, 2)
void attn_causal14(const __bf16* __restrict__ qkv, const __bf16* __restrict__ vt,
                   __bf16* __restrict__ yb) {
  __shared__ __align__(16) char Kbuf[2][8192];   // K[kv][d], chunk-swizzled
  __shared__ __align__(16) char Vbuf[2][8192];   // Vt[d][kv], chunk-swizzled
  __shared__ __align__(16) char Pbuf[2][4096];   // per-wave P[32][64], psw-swizzled

  const int tid = threadIdx.x;
  const int lane = tid & 63, w = tid >> 6;       // w in {0,1}
  const int L = blockIdx.x;
  const int bh = L & 31;
  const int p = L >> 5;
  const int chunk = (p < 16) ? p : 47 - p;       // v4 fold: CU-sum constant
  const int b = bh >> 4, h = bh & 15;
  const size_t rowbase = (size_t)b * TT;
  const int q0 = chunk * 64 + w * 32;            // wave's first q row
  const int fr = lane & 15, g = lane >> 4;
  const int ntiles = chunk + 1;

  bf16x8 qf[2][2];
#pragma unroll
  for (int m2 = 0; m2 < 2; m2++)
#pragma unroll
    for (int kc = 0; kc < 2; kc++)
      qf[m2][kc] = *(const bf16x8*)(qkv + (rowbase + q0 + m2 * 16 + fr) * QKVN + h * HD + kc * 32 + g * 8);

  bf16x8 ones;
#pragma unroll
  for (int j = 0; j < 8; j++) ones[j] = (__bf16)1.0f;

  f32x4 o[2][4];
  f32x4 lacc[2];
  float m[2][4];
#pragma unroll
  for (int m2 = 0; m2 < 2; m2++) {
#pragma unroll
    for (int n = 0; n < 4; n++)
#pragma unroll
      for (int r = 0; r < 4; r++) o[m2][n][r] = 0.0f;
#pragma unroll
    for (int r = 0; r < 4; r++) { lacc[m2][r] = 0.0f; m[m2][r] = -1e30f; }
  }

  // 8 gload_lds per thread per stage (128 thr x 8 x 16B = 16KB K+V)
  auto stageKV = [&](int kt, int buf) {
#pragma unroll
    for (int i = 0; i < 4; i++) {
      const int c = tid + i * 128;
      const int row = c >> 3;
      const int c16 = (c & 7) ^ (row & 7);
      gload_lds16(qkv + (rowbase + kt * 64 + row) * QKVN + EMB + h * HD + c16 * 8,
                  Kbuf[buf] + c * 16);
    }
#pragma unroll
    for (int i = 0; i < 4; i++) {
      const int c = tid + i * 128;
      const int row = c >> 3;
      const int c16 = (c & 7) ^ (row & 7);
      gload_lds16(vt + ((size_t)bh * HD + row) * TT + kt * 64 + c16 * 8,
                  Vbuf[buf] + c * 16);
    }
  };

  auto doQK = [&](int buf, f32x4 (&s)[2][4]) {
    const char* Kc = Kbuf[buf];
    bf16x8 kf[4][2];
#pragma unroll
    for (int n = 0; n < 4; n++)
#pragma unroll
      for (int kc = 0; kc < 2; kc++) {
        const int row = n * 16 + fr;
        kf[n][kc] = *(const bf16x8*)(Kc + row * 128 + (((kc << 2) | g) ^ (row & 7)) * 16);
      }
    __builtin_amdgcn_s_setprio(1);
#pragma unroll
    for (int m2 = 0; m2 < 2; m2++)
#pragma unroll
      for (int n = 0; n < 4; n++) {
#pragma unroll
        for (int r = 0; r < 4; r++) s[m2][n][r] = 0.0f;
#pragma unroll
        for (int kc = 0; kc < 2; kc++)
          s[m2][n] = __builtin_amdgcn_mfma_f32_16x16x32_bf16(qf[m2][kc], kf[n][kc], s[m2][n], 0, 0, 0);
      }
    __builtin_amdgcn_s_setprio(0);
  };

  auto doSoftmax = [&](int kt, f32x4 (&s)[2][4]) {
    const int kv0 = kt * 64;
    if (kt == chunk) {                           // diagonal tile
#pragma unroll
      for (int m2 = 0; m2 < 2; m2++)
#pragma unroll
        for (int n = 0; n < 4; n++)
#pragma unroll
          for (int r = 0; r < 4; r++) {
            const int qg = q0 + m2 * 16 + g * 4 + r;
            const int kg = kv0 + n * 16 + fr;
            if (kg > qg) s[m2][n][r] = -1e30f;
          }
    }
    float pm[2][4];
#pragma unroll
    for (int m2 = 0; m2 < 2; m2++)
#pragma unroll
      for (int r = 0; r < 4; r++)
        pm[m2][r] = fmaxf(fmaxf(s[m2][0][r], s[m2][1][r]), fmaxf(s[m2][2][r], s[m2][3][r]));
    bool okl = true;
#pragma unroll
    for (int m2 = 0; m2 < 2; m2++)
#pragma unroll
      for (int r = 0; r < 4; r++)
        okl = okl && (pm[m2][r] <= m[m2][r] + THR);
    if (!__all(okl)) {
#pragma unroll
      for (int m2 = 0; m2 < 2; m2++)
#pragma unroll
        for (int r = 0; r < 4; r++) {
          float rm = pm[m2][r];
#pragma unroll
          for (int d = 1; d < 16; d <<= 1) rm = fmaxf(rm, __shfl_xor(rm, d, 16));
          const float nm = fmaxf(m[m2][r], rm);
          const float f = __builtin_amdgcn_exp2f(m[m2][r] - nm);
          m[m2][r] = nm;
          lacc[m2][r] *= f;
#pragma unroll
          for (int n = 0; n < 4; n++) o[m2][n][r] *= f;
        }
    }
#pragma unroll
    for (int m2 = 0; m2 < 2; m2++)
#pragma unroll
      for (int n = 0; n < 4; n++)
#pragma unroll
        for (int r = 0; r < 4; r++) {
          const float e = __builtin_amdgcn_exp2f(s[m2][n][r] - m[m2][r]);
          const int row = m2 * 16 + g * 4 + r;
          *(__bf16*)(Pbuf[w] + row * 128 + (((n * 16 + fr) * 2) ^ psw(row))) = (__bf16)e;
        }
  };

  auto doPV = [&](int buf) {
    const char* Vc = Vbuf[buf];
    bf16x8 pa[2][2];
#pragma unroll
    for (int m2 = 0; m2 < 2; m2++)
#pragma unroll
      for (int kc = 0; kc < 2; kc++) {
        const int row = m2 * 16 + fr;
        pa[m2][kc] = *(const bf16x8*)(Pbuf[w] + row * 128 + ((kc * 64 + g * 16) ^ psw(row)));
      }
    bf16x8 vb[4][2];
#pragma unroll
    for (int n = 0; n < 4; n++)
#pragma unroll
      for (int kc = 0; kc < 2; kc++) {
        const int row = n * 16 + fr;
        vb[n][kc] = *(const bf16x8*)(Vc + row * 128 + (((kc << 2) | g) ^ (row & 7)) * 16);
      }
    __builtin_amdgcn_s_setprio(1);
#pragma unroll
    for (int m2 = 0; m2 < 2; m2++)
#pragma unroll
      for (int kc = 0; kc < 2; kc++) {
        lacc[m2] = __builtin_amdgcn_mfma_f32_16x16x32_bf16(pa[m2][kc], ones, lacc[m2], 0, 0, 0);
#pragma unroll
        for (int n = 0; n < 4; n++)
          o[m2][n] = __builtin_amdgcn_mfma_f32_16x16x32_bf16(pa[m2][kc], vb[n][kc], o[m2][n], 0, 0, 0);
      }
    __builtin_amdgcn_s_setprio(0);
  };

  // ---- prologue ----
  stageKV(0, 0);
  __syncthreads();                   // drains DMA: tile 0 in LDS

  int cur = 0;
  for (int t = 0; t < ntiles; t++) {
    if (t + 1 < ntiles) stageKV(t + 1, cur ^ 1);   // DMA lands during this phase

    f32x4 s[2][4];
    doQK(cur, s);
    doSoftmax(t, s);
    doPV(cur);

    __syncthreads();                 // waves done with cur; next tile drained
    cur ^= 1;
  }

#pragma unroll
  for (int m2 = 0; m2 < 2; m2++)
#pragma unroll
    for (int r = 0; r < 4; r++) {
      const float inv = __builtin_amdgcn_rcpf(lacc[m2][r]);
      const int q = q0 + m2 * 16 + g * 4 + r;
#pragma unroll
      for (int n = 0; n < 4; n++) {
        const int d = n * 16 + fr;
        yb[(rowbase + q) * EMB + h * HD + d] = (__bf16)(o[m2][n][r] * inv);
      }
    }
}

extern "C" void kernel_launch(void* const* d_in, const int* in_sizes, int n_in,
                              void* d_out, int out_size, void* d_ws, size_t ws_size,
                              hipStream_t stream) {
  const float* x     = (const float*)d_in[0];
  const float* w_qkv = (const float*)d_in[1];
  const float* w_out = (const float*)d_in[2];
  float* out = (float*)d_out;

  char* ws = (char*)d_ws;
  __bf16* xb    = (__bf16*)(ws);                 // dead after gemm1 -> reused as yb
  __bf16* wqkvb = (__bf16*)(ws + (8ull  << 20));
  __bf16* wob   = (__bf16*)(ws + (14ull << 20));
  __bf16* qkvb  = (__bf16*)(ws + (16ull << 20));
  __bf16* vtb   = (__bf16*)(ws + (40ull << 20));
  __bf16* yb    = xb;

  cvt_all<<<4096, 256, 0, stream>>>(x, w_qkv, w_out, xb, wqkvb, wob);
  gemm_bt<1><<<dim3(QKVN / 128, NROWS / 128), 256, 0, stream>>>(xb, wqkvb, qkvb, vtb, NROWS, QKVN, EMB);
  attn_causal14<<<1024, 128, 0, stream>>>(qkvb, vtb, yb);
  gemm_bt<0><<<dim3(EMB / 128, NROWS / 128), 256, 0, stream>>>(yb, wob, out, nullptr, NROWS, EMB, EMB);
}